// Round 2
// baseline (117.571 us; speedup 1.0000x reference)
//
#include <hip/hip_runtime.h>
#include <hip/hip_cooperative_groups.h>

namespace cg = cooperative_groups;

#define VOCAB 30522
#define D     768
#define NC    9
#define NROWS (32 * 512)     // 16384
#define TPB   256
#define GRID  512
#define RPB   (NROWS / GRID) // 32 rows per block

// Workspace layout (bytes):
//   [0, 244176)        seg tables: seg_sum[VOCAB] then seg_cnt[VOCAB]
//   [244176, 244240)   wsum2 (fallback path only)
//   [244240, 834064)   partial [NROWS*9] (fallback path only)
#define WS_WSUM2_OFF   (2 * VOCAB * 4)
#define WS_PARTIAL_OFF (WS_WSUM2_OFF + 64)

// ---------------------------------------------------------------------------
// Full-wave (64-lane) sum via DPP — pure VALU, no DS pipe, no readlane.
// Result is valid in lane 63.
// ---------------------------------------------------------------------------
__device__ __forceinline__ float wave_reduce_add(float x) {
#define DPP_STEP(ctrl)                                                         \
    do {                                                                       \
        int t_ = __builtin_amdgcn_update_dpp(0, __float_as_int(x), (ctrl),     \
                                             0xf, 0xf, true);                  \
        x += __int_as_float(t_);                                               \
    } while (0)
    DPP_STEP(0x111); // row_shr:1
    DPP_STEP(0x112); // row_shr:2
    DPP_STEP(0x114); // row_shr:4
    DPP_STEP(0x118); // row_shr:8   -> lane15 of each 16-row has row sum
    DPP_STEP(0x142); // row_bcast:15 -> lane31 = sum(0..31), lane63 = sum(32..63)
    DPP_STEP(0x143); // row_bcast:31 -> lane63 = total
#undef DPP_STEP
    return x;
}

// Lane `lane` owns dims [lane*12, lane*12+12): 27 coalesced float4 of W.
__device__ __forceinline__ void load_warr(const float* __restrict__ W, int lane,
                                          float (&warr)[108]) {
    const float4* wp = (const float4*)(W + lane * 108); // 432B per lane, 16B aligned
    #pragma unroll
    for (int i = 0; i < 27; ++i) {
        float4 v = wp[i];
        warr[4*i+0] = v.x; warr[4*i+1] = v.y; warr[4*i+2] = v.z; warr[4*i+3] = v.w;
    }
}

// acc[0..8] = partial dots of this row with W[:,c]; acc[9] = partial row sum.
__device__ __forceinline__ void compute_row(const float* __restrict__ h, int row,
                                            int lane, const float (&warr)[108],
                                            float (&acc)[10]) {
    const float4* hv = (const float4*)(h + (size_t)row * D + lane * 12);
    float4 v0 = hv[0], v1 = hv[1], v2 = hv[2];
    float vals[12] = {v0.x, v0.y, v0.z, v0.w,
                      v1.x, v1.y, v1.z, v1.w,
                      v2.x, v2.y, v2.z, v2.w};
    #pragma unroll
    for (int t = 0; t < 10; ++t) acc[t] = 0.f;
    #pragma unroll
    for (int i = 0; i < 12; ++i) {
        acc[9] += vals[i];
        #pragma unroll
        for (int c = 0; c < 9; ++c)
            acc[c] = fmaf(vals[i], warr[i * 9 + c], acc[c]);
    }
}

// wsum2[c] = sum_{d>=768} W[d,c], computed by one 256-thread block.
// wave w covers c = w, w+4 (and c=8 for wave 0). Result written by lane 63.
__device__ __forceinline__ void compute_wsum2(const float* __restrict__ W,
                                              int lane, int wave, float* dst) {
    float s0 = 0.f, s1 = 0.f, s2 = 0.f;
    #pragma unroll
    for (int k = 0; k < 12; ++k) {
        const float* rw = W + (size_t)(D + lane + 64 * k) * NC;
        s0 += rw[wave];
        s1 += rw[wave + 4];
        if (wave == 0) s2 += rw[8];
    }
    s0 = wave_reduce_add(s0);
    s1 = wave_reduce_add(s1);
    s2 = wave_reduce_add(s2);
    if (lane == 63) {
        dst[wave] = s0;
        dst[wave + 4] = s1;
        if (wave == 0) dst[8] = s2;
    }
}

// ---------------------------------------------------------------------------
// Single cooperative kernel: zero+wsum2 | grid.sync | row pass | grid.sync |
// finalize from LDS partials.
// ---------------------------------------------------------------------------
__global__ __launch_bounds__(TPB, 2) void fused_kernel(
    const float* __restrict__ h, const float* __restrict__ W,
    const int* __restrict__ ids, const float* __restrict__ bias,
    float* __restrict__ seg,   // [2*VOCAB]: sums then counts
    float* __restrict__ out)
{
    __shared__ float s_part[RPB][NC];
    __shared__ float s_ctx[RPB];
    __shared__ float s_wsum2[NC];
    __shared__ int   s_id[RPB];

    const int tid  = threadIdx.x;
    const int lane = tid & 63;
    const int wave = tid >> 6;
    const int bid  = blockIdx.x;

    // ---- Phase 0: zero seg tables; per-block wsum2 into LDS; hoist W.
    for (int i = bid * TPB + tid; i < 2 * VOCAB; i += GRID * TPB)
        seg[i] = 0.f;
    compute_wsum2(W, lane, wave, s_wsum2);

    float warr[108];
    load_warr(W, lane, warr);

    cg::this_grid().sync();

    // ---- Phase 1: stream h once; atomics + LDS partials.
    #pragma unroll 2
    for (int r = wave; r < RPB; r += 4) {
        const int row = bid * RPB + r;
        float acc[10];
        compute_row(h, row, lane, warr, acc);
        #pragma unroll
        for (int t = 0; t < 10; ++t) acc[t] = wave_reduce_add(acc[t]);
        if (lane == 63) {
            const int id = ids[row];
            s_id[r] = id;
            #pragma unroll
            for (int c = 0; c < 9; ++c) s_part[r][c] = acc[c];
            atomicAdd(seg + id,         acc[9] * (1.f / 768.f));
            atomicAdd(seg + VOCAB + id, 1.f);
        }
    }

    cg::this_grid().sync();

    // ---- Phase 2: finalize this block's 32 rows from LDS.
    if (tid < RPB) {
        const int id = s_id[tid];
        float ssum = __hip_atomic_load(seg + id,         __ATOMIC_RELAXED,
                                       __HIP_MEMORY_SCOPE_AGENT);
        float scnt = __hip_atomic_load(seg + VOCAB + id, __ATOMIC_RELAXED,
                                       __HIP_MEMORY_SCOPE_AGENT);
        s_ctx[tid] = ssum / fmaxf(scnt, 1.f);
    }
    __syncthreads();
    for (int t = tid; t < RPB * NC; t += TPB) {
        const int r = t / NC, c = t - r * NC;
        out[(size_t)bid * RPB * NC + t] = s_part[r][c] + s_ctx[r] * s_wsum2[c] + bias[c];
    }
}

// ---------------------------------------------------------------------------
// Non-cooperative fallback (3 dispatches), used only if the cooperative
// launch is rejected (e.g. unsupported under graph capture).
// ---------------------------------------------------------------------------
__global__ __launch_bounds__(TPB) void fb_setup(const float* __restrict__ W,
                                                float* __restrict__ seg,
                                                float* __restrict__ wsum2g) {
    const int gid = blockIdx.x * TPB + threadIdx.x;
    for (int i = gid; i < 2 * VOCAB; i += gridDim.x * TPB) seg[i] = 0.f;
    if (blockIdx.x == 0)
        compute_wsum2(W, threadIdx.x & 63, threadIdx.x >> 6, wsum2g);
}

__global__ __launch_bounds__(TPB, 2) void fb_row(const float* __restrict__ h,
                                                 const float* __restrict__ W,
                                                 const int* __restrict__ ids,
                                                 float* __restrict__ seg,
                                                 float* __restrict__ partial) {
    const int lane = threadIdx.x & 63;
    const int wave = threadIdx.x >> 6;
    float warr[108];
    load_warr(W, lane, warr);
    for (int row = blockIdx.x * 4 + wave; row < NROWS; row += gridDim.x * 4) {
        float acc[10];
        compute_row(h, row, lane, warr, acc);
        #pragma unroll
        for (int t = 0; t < 10; ++t) acc[t] = wave_reduce_add(acc[t]);
        if (lane == 63) {
            const int id = ids[row];
            #pragma unroll
            for (int c = 0; c < 9; ++c) partial[(size_t)row * NC + c] = acc[c];
            atomicAdd(seg + id,         acc[9] * (1.f / 768.f));
            atomicAdd(seg + VOCAB + id, 1.f);
        }
    }
}

__global__ __launch_bounds__(TPB) void fb_fin(const float* __restrict__ partial,
                                              const int* __restrict__ ids,
                                              const float* __restrict__ seg,
                                              const float* __restrict__ wsum2g,
                                              const float* __restrict__ bias,
                                              float* __restrict__ out) {
    const int t = blockIdx.x * TPB + threadIdx.x;
    if (t >= NROWS * NC) return;
    const int row = t / NC, c = t - row * NC;
    const int id = ids[row];
    const float ctx = seg[id] / fmaxf(seg[VOCAB + id], 1.f);
    out[t] = partial[t] + ctx * wsum2g[c] + bias[c];
}

extern "C" void kernel_launch(void* const* d_in, const int* in_sizes, int n_in,
                              void* d_out, int out_size, void* d_ws, size_t ws_size,
                              hipStream_t stream) {
    const int*   ids = (const int*)  d_in[0];  // batch [32,512] int32
    const float* h   = (const float*)d_in[1];  // [32,512,768] f32
    const float* W   = (const float*)d_in[2];  // [1536,9] f32
    const float* b   = (const float*)d_in[3];  // [9] f32
    float* out = (float*)d_out;                // [32,512,9] f32
    float* seg = (float*)d_ws;                 // [2*VOCAB] f32

    void* args[6] = { (void*)&h, (void*)&W, (void*)&ids,
                      (void*)&b, (void*)&seg, (void*)&out };
    hipError_t err = hipLaunchCooperativeKernel((void*)fused_kernel,
                                                dim3(GRID), dim3(TPB),
                                                args, 0, stream);
    if (err != hipSuccess) {
        float* wsum2g  = (float*)((char*)d_ws + WS_WSUM2_OFF);
        float* partial = (float*)((char*)d_ws + WS_PARTIAL_OFF);
        fb_setup<<<240, TPB, 0, stream>>>(W, seg, wsum2g);
        fb_row<<<512, TPB, 0, stream>>>(h, W, ids, seg, partial);
        fb_fin<<<(NROWS * NC + TPB - 1) / TPB, TPB, 0, stream>>>(
            partial, ids, seg, wsum2g, b, out);
    }
}

// Round 3
// 28.254 us; speedup vs baseline: 4.1613x; 4.1613x over previous
//
#include <hip/hip_runtime.h>

#define VOCAB 30522
#define D     768
#define NC    9
#define NROWS 16384          // 32*512
#define TPB   256
#define G_ROW 512            // 4 waves/block * 8 rows/wave * 512 = 16384 rows
#define RPW   8

// Workspace (floats): seg_sum[VOCAB] | seg_cnt[VOCAB] | wsum2[16]
// Total 244240 bytes (<= ws_size, proven by rounds 1-2).

// ---------------------------------------------------------------------------
// Full-wave (64-lane) sum via DPP — pure VALU. Result valid in lane 63.
// (Sequence numerically validated in round 2.)
// ---------------------------------------------------------------------------
__device__ __forceinline__ float wave_reduce_add(float x) {
#define DPP_STEP(ctrl)                                                         \
    do {                                                                       \
        int t_ = __builtin_amdgcn_update_dpp(0, __float_as_int(x), (ctrl),     \
                                             0xf, 0xf, true);                  \
        x += __int_as_float(t_);                                               \
    } while (0)
    DPP_STEP(0x111); // row_shr:1
    DPP_STEP(0x112); // row_shr:2
    DPP_STEP(0x114); // row_shr:4
    DPP_STEP(0x118); // row_shr:8
    DPP_STEP(0x142); // row_bcast:15
    DPP_STEP(0x143); // row_bcast:31 -> lane63 = total
#undef DPP_STEP
    return x;
}

// wsum2[c] = sum_{d>=768} W[d,c], one 256-thread block.
__device__ __forceinline__ void compute_wsum2(const float* __restrict__ W,
                                              int lane, int wave, float* dst) {
    float s0 = 0.f, s1 = 0.f, s2 = 0.f;
    #pragma unroll
    for (int k = 0; k < 12; ++k) {
        const float* rw = W + (size_t)(D + lane + 64 * k) * NC;
        s0 += rw[wave];
        s1 += rw[wave + 4];
        if (wave == 0) s2 += rw[8];
    }
    s0 = wave_reduce_add(s0);
    s1 = wave_reduce_add(s1);
    s2 = wave_reduce_add(s2);
    if (lane == 63) {
        dst[wave]     = s0;
        dst[wave + 4] = s1;
        if (wave == 0) dst[8] = s2;
    }
}

// ---------------------------------------------------------------------------
// Setup: zero seg tables (15261 float4) + wsum2 (last block).
// ---------------------------------------------------------------------------
__global__ __launch_bounds__(TPB) void setup_kernel(const float* __restrict__ W,
                                                    float* __restrict__ seg,
                                                    float* __restrict__ wsum2) {
    const int gid = blockIdx.x * TPB + threadIdx.x;
    if (gid < (2 * VOCAB) / 4)
        ((float4*)seg)[gid] = make_float4(0.f, 0.f, 0.f, 0.f);
    if (blockIdx.x == gridDim.x - 1)
        compute_wsum2(W, threadIdx.x & 63, threadIdx.x >> 6, wsum2);
}

// FMA one 256-float-chunk quarter: v holds 4 consecutive h values for dims
// d..d+3; wk[36] holds W[d..d+3][0..8] (chunk layout: wk[9*j+c]).
__device__ __forceinline__ void fma_chunk(float (&acc)[10], float4 v,
                                          const float (&wk)[36]) {
    const float vv[4] = {v.x, v.y, v.z, v.w};
    #pragma unroll
    for (int j = 0; j < 4; ++j) {
        acc[9] += vv[j];
        #pragma unroll
        for (int c = 0; c < 9; ++c)
            acc[c] = fmaf(vv[j], wk[9 * j + c], acc[c]);
    }
}

// ---------------------------------------------------------------------------
// Row pass: wave per row (8 rows/wave, 2-row unroll). Coalesced h loads
// (lane + 64k float4 layout). W hoisted to registers via 27 coalesced float4.
// Writes partial dots straight into out[]; row-mean atomics into seg tables.
// ---------------------------------------------------------------------------
__global__ __launch_bounds__(TPB, 2) void row_kernel(
    const float* __restrict__ h, const float* __restrict__ W,
    const int* __restrict__ ids, float* __restrict__ seg,
    float* __restrict__ out)
{
    const int lane = threadIdx.x & 63;
    const int wave = threadIdx.x >> 6;
    const int base = (blockIdx.x * 4 + wave) * RPW;

    // W chunk for this lane: dims 4*(lane+64k)..+3 for k=0..2 -> 3x36 floats,
    // loaded as 27 coalesced float4 (lane stride 144B, all compile-time idx).
    float wf[3][36];
    #pragma unroll
    for (int k = 0; k < 3; ++k) {
        const float4* wp = (const float4*)W + (size_t)(lane + 64 * k) * 9;
        #pragma unroll
        for (int i = 0; i < 9; ++i) {
            float4 v = wp[i];
            wf[k][4 * i + 0] = v.x; wf[k][4 * i + 1] = v.y;
            wf[k][4 * i + 2] = v.z; wf[k][4 * i + 3] = v.w;
        }
    }

    #pragma unroll
    for (int r = 0; r < RPW; r += 2) {
        const int rA = base + r, rB = base + r + 1;
        const float4* hA = (const float4*)h + (size_t)rA * (D / 4) + lane;
        const float4* hB = (const float4*)h + (size_t)rB * (D / 4) + lane;
        float4 a0 = hA[0], a1 = hA[64], a2 = hA[128];
        float4 b0 = hB[0], b1 = hB[64], b2 = hB[128];
        const int idA = ids[rA];   // wave-uniform -> scalar load
        const int idB = ids[rB];

        float accA[10], accB[10];
        #pragma unroll
        for (int t = 0; t < 10; ++t) { accA[t] = 0.f; accB[t] = 0.f; }

        fma_chunk(accA, a0, wf[0]); fma_chunk(accA, a1, wf[1]); fma_chunk(accA, a2, wf[2]);
        fma_chunk(accB, b0, wf[0]); fma_chunk(accB, b1, wf[1]); fma_chunk(accB, b2, wf[2]);

        // Interleave the two reduction chains for ILP across DPP latency.
        #pragma unroll
        for (int t = 0; t < 10; ++t) {
            accA[t] = wave_reduce_add(accA[t]);
            accB[t] = wave_reduce_add(accB[t]);
        }

        if (lane == 63) {
            #pragma unroll
            for (int c = 0; c < 9; ++c) out[(size_t)rA * NC + c] = accA[c];
            #pragma unroll
            for (int c = 0; c < 9; ++c) out[(size_t)rB * NC + c] = accB[c];
            atomicAdd(seg + idA,         accA[9] * (1.f / 768.f));
            atomicAdd(seg + VOCAB + idA, 1.f);
            atomicAdd(seg + idB,         accB[9] * (1.f / 768.f));
            atomicAdd(seg + VOCAB + idB, 1.f);
        }
    }
}

// ---------------------------------------------------------------------------
// Finalize: out[e] += ctx(row)*wsum2[c] + bias[c].  Coalesced RMW of out.
// ---------------------------------------------------------------------------
__global__ __launch_bounds__(TPB) void finalize_kernel(
    const int* __restrict__ ids, const float* __restrict__ seg,
    const float* __restrict__ wsum2, const float* __restrict__ bias,
    float* __restrict__ out)
{
    const int e   = blockIdx.x * TPB + threadIdx.x;   // grid sized exactly
    const int row = e / NC;
    const int c   = e - row * NC;
    const int id  = ids[row];
    const float ctx = seg[id] / fmaxf(seg[VOCAB + id], 1.f);
    out[e] += ctx * wsum2[c] + bias[c];
}

extern "C" void kernel_launch(void* const* d_in, const int* in_sizes, int n_in,
                              void* d_out, int out_size, void* d_ws, size_t ws_size,
                              hipStream_t stream) {
    const int*   ids = (const int*)  d_in[0];  // [32,512] int32
    const float* h   = (const float*)d_in[1];  // [32,512,768] f32
    const float* W   = (const float*)d_in[2];  // [1536,9] f32
    const float* b   = (const float*)d_in[3];  // [9] f32
    float* out = (float*)d_out;                // [32,512,9] f32

    float* seg   = (float*)d_ws;               // [2*VOCAB]
    float* wsum2 = seg + 2 * VOCAB;            // [16]

    setup_kernel<<<60, TPB, 0, stream>>>(W, seg, wsum2);
    row_kernel<<<G_ROW, TPB, 0, stream>>>(h, W, ids, seg, out);
    finalize_kernel<<<(NROWS * NC) / TPB, TPB, 0, stream>>>(ids, seg, wsum2, b, out);
}